// Round 17
// baseline (82.799 us; speedup 1.0000x reference)
//
#include <hip/hip_runtime.h>
#include <hip/hip_bf16.h>
#include <stdint.h>

#define D_MODEL 256
#define NHEAD   8
#define DK      32
#define BATCH   4
#define SEQ     2048
#define MROWS   (BATCH*SEQ)   // 8192

typedef float  f32x4  __attribute__((ext_vector_type(4)));
typedef __bf16 bf16x8 __attribute__((ext_vector_type(8)));

__device__ __forceinline__ unsigned short f2bf(float f) {
  unsigned int u = __float_as_uint(f);
  unsigned int r = (u + 0x7FFFu + ((u >> 16) & 1u)) >> 16;
  return (unsigned short)r;
}
__device__ __forceinline__ float bfbits2f(unsigned short b) {
  return __uint_as_float(((unsigned int)b) << 16);
}

__device__ __forceinline__ f32x4 mfma16(bf16x8 a, bf16x8 b, f32x4 c) {
  return __builtin_amdgcn_mfma_f32_16x16x32_bf16(a, b, c, 0, 0, 0);
}
__device__ __forceinline__ unsigned int cvtpk(float lo, float hi) {
  unsigned int r;
  asm("v_cvt_pk_bf16_f32 %0, %1, %2" : "=v"(r) : "v"(lo), "v"(hi));
  return r;
}

// scale folded into Wq/bq: (1/sqrt(32)) * log2(e)
#define QSCALE 0.2550599440097021f

// ---------------- fused QKV projection GEMM (128x64 tiles, no grid tail) -----
// Grid (64,12) = 768 blocks = exactly 3 full occupancy rounds on 256 CUs
// (vs 384 = 1.5 rounds before). y -> mat = y>>2 (0=Q,1=K,2=V), ncol=(y&3)*64;
// each block's 64 output columns lie entirely within one matrix.
// W casts fused into B staging; x cast fused into A staging (both r14-proven).
// Q/K out: [bh][s][32]; V out: transposed + w-scaled: Vt[bh][d][s] = w_s*V[s][d]
// Blocks with blockIdx.y==0 also materialize wb[] (bf16 w) for attn's den.
__global__ __launch_bounds__(256) void qkv_gemm(
    const float* __restrict__ x, const float* __restrict__ cx,
    const float* __restrict__ Wq, const float* __restrict__ Wk,
    const float* __restrict__ Wv,
    const float* __restrict__ bq, const float* __restrict__ bk_, const float* __restrict__ bv,
    unsigned short* __restrict__ Qb, unsigned short* __restrict__ Kb,
    unsigned short* __restrict__ Vt, unsigned short* __restrict__ wb) {
  __shared__ __align__(16) unsigned short As[128 * 72];
  __shared__ __align__(16) unsigned short Bs[64 * 72];
  const int tid = threadIdx.x, lane = tid & 63, wid = tid >> 6;
  const int bm = blockIdx.x * 128;
  const int mat = blockIdx.y >> 2;
  const int ncol = (blockIdx.y & 3) * 64;
  const float* Wf = (mat == 0) ? Wq : ((mat == 1) ? Wk : Wv);
  const float* bias = (mat == 0) ? bq : ((mat == 1) ? bk_ : bv);
  const float bscale = (mat == 0) ? QSCALE : 1.0f;
  const int waveM = wid * 32;

  if (blockIdx.y == 0 && tid < 32) {
    int s = blockIdx.x * 32 + tid;
    wb[s] = (s == 0) ? (unsigned short)0 : f2bf(fabsf(cx[s] - cx[s - 1]));
  }

  f32x4 acc[2][4] = {};
  for (int kt = 0; kt < 4; ++kt) {
    __syncthreads();
#pragma unroll
    for (int p = 0; p < 4; ++p) {
      int c = p * 256 + tid;
      int r = c >> 3, kc = c & 7;
      const float* xp = x + (size_t)(bm + r) * 256 + kt * 64 + kc * 8;
      float4 f0 = *reinterpret_cast<const float4*>(xp);
      float4 f1 = *reinterpret_cast<const float4*>(xp + 4);
      ushort4 h0, h1;
      h0.x = f2bf(f0.x); h0.y = f2bf(f0.y); h0.z = f2bf(f0.z); h0.w = f2bf(f0.w);
      h1.x = f2bf(f1.x); h1.y = f2bf(f1.y); h1.z = f2bf(f1.z); h1.w = f2bf(f1.w);
      *reinterpret_cast<ushort4*>(&As[r * 72 + kc * 8])     = h0;
      *reinterpret_cast<ushort4*>(&As[r * 72 + kc * 8 + 4]) = h1;
    }
#pragma unroll
    for (int p = 0; p < 2; ++p) {
      int c = p * 256 + tid;
      int r = c >> 3, kc = c & 7;
      const float* wp_ = Wf + (size_t)(ncol + r) * 256 + kt * 64 + kc * 8;
      float4 g0 = *reinterpret_cast<const float4*>(wp_);
      float4 g1 = *reinterpret_cast<const float4*>(wp_ + 4);
      ushort4 b0, b1;
      b0.x = f2bf(g0.x * bscale); b0.y = f2bf(g0.y * bscale);
      b0.z = f2bf(g0.z * bscale); b0.w = f2bf(g0.w * bscale);
      b1.x = f2bf(g1.x * bscale); b1.y = f2bf(g1.y * bscale);
      b1.z = f2bf(g1.z * bscale); b1.w = f2bf(g1.w * bscale);
      *reinterpret_cast<ushort4*>(&Bs[r * 72 + kc * 8])     = b0;
      *reinterpret_cast<ushort4*>(&Bs[r * 72 + kc * 8 + 4]) = b1;
    }
    __syncthreads();
#pragma unroll
    for (int ks = 0; ks < 2; ++ks) {
      bf16x8 af[2], bf[4];
#pragma unroll
      for (int m = 0; m < 2; ++m)
        af[m] = *reinterpret_cast<const bf16x8*>(&As[(waveM + m * 16 + (lane & 15)) * 72 + ks * 32 + (lane >> 4) * 8]);
#pragma unroll
      for (int n = 0; n < 4; ++n)
        bf[n] = *reinterpret_cast<const bf16x8*>(&Bs[(n * 16 + (lane & 15)) * 72 + ks * 32 + (lane >> 4) * 8]);
#pragma unroll
      for (int m = 0; m < 2; ++m)
#pragma unroll
        for (int n = 0; n < 4; ++n) acc[m][n] = mfma16(af[m], bf[n], acc[m][n]);
    }
  }
#pragma unroll
  for (int m = 0; m < 2; ++m) {
    int i0 = bm + waveM + m * 16 + (lane >> 4) * 4;  // row of r=0 (mult of 4)
    int b = i0 >> 11, s = i0 & 2047;
    float wv4[4] = {0.f, 0.f, 0.f, 0.f};
    if (mat == 2) {
      float cm = (s > 0) ? cx[s - 1] : 0.0f;
      float c0 = cx[s], c1 = cx[s + 1], c2 = cx[s + 2], c3 = cx[s + 3];
      wv4[0] = (s > 0) ? bfbits2f(f2bf(fabsf(c0 - cm))) : 0.0f;
      wv4[1] = bfbits2f(f2bf(fabsf(c1 - c0)));
      wv4[2] = bfbits2f(f2bf(fabsf(c2 - c1)));
      wv4[3] = bfbits2f(f2bf(fabsf(c3 - c2)));
    }
#pragma unroll
    for (int n = 0; n < 4; ++n) {
      int j = ncol + n * 16 + (lane & 15);
      float bias_v = bias[j] * bscale;
      int h = j >> 5, d = j & 31;
      if (mat == 2) {
        ushort4 pk;
        pk.x = f2bf((acc[m][n][0] + bias_v) * wv4[0]);
        pk.y = f2bf((acc[m][n][1] + bias_v) * wv4[1]);
        pk.z = f2bf((acc[m][n][2] + bias_v) * wv4[2]);
        pk.w = f2bf((acc[m][n][3] + bias_v) * wv4[3]);
        *reinterpret_cast<ushort4*>(&Vt[((b * NHEAD + h) * DK + d) * SEQ + s]) = pk;
      } else {
        unsigned short* dst = (mat == 0) ? Qb : Kb;
#pragma unroll
        for (int r = 0; r < 4; ++r)
          dst[((b * NHEAD + h) * SEQ + s + r) * DK + d] = f2bf(acc[m][n][r] + bias_v);
      }
    }
  }
}

// ---------------- fused weighted attention — VERBATIM round-8/14 (55.9us) ----
__global__ __launch_bounds__(256, 4) void attn_kernel(
    const unsigned short* __restrict__ Qb, const unsigned short* __restrict__ Kb,
    const unsigned short* __restrict__ Vt, const unsigned short* __restrict__ wb,
    unsigned short* __restrict__ AOb) {
  __shared__ float ol[4][32][36];
  __shared__ __align__(16) unsigned short ps[4][2][32][40];
  const int tid = threadIdx.x, lane = tid & 63, wid = tid >> 6;
  const int g = lane >> 4, lq = lane & 15;
  const int bh = blockIdx.y;
  const int q0 = blockIdx.x * 32;

  const unsigned short* Qbh = Qb + bh * SEQ * DK;
  const unsigned short* Kbh = Kb + bh * SEQ * DK;
  const unsigned short* Vbh = Vt + bh * DK * SEQ;

  bf16x8 qf[2];
  qf[0] = *reinterpret_cast<const bf16x8*>(Qbh + (q0 + lq) * DK + g * 8);
  qf[1] = *reinterpret_cast<const bf16x8*>(Qbh + (q0 + 16 + lq) * DK + g * 8);

  f32x4 o[2][2] = {};   // [q-tile m][d-tile n]
  f32x4 den[2] = {};
  const f32x4 zero4 = {0.f, 0.f, 0.f, 0.f};
  const int sbase = wid * (SEQ / 4);

#pragma unroll 2
  for (int st = 0; st < (SEQ / 4) / 32; ++st) {
    const int s0 = sbase + st * 32;
    bf16x8 kf0 = *reinterpret_cast<const bf16x8*>(Kbh + (s0 + lq) * DK + g * 8);
    bf16x8 kf1 = *reinterpret_cast<const bf16x8*>(Kbh + (s0 + 16 + lq) * DK + g * 8);

    unsigned short* pb = &ps[wid][st & 1][0][0];

#pragma unroll
    for (int m = 0; m < 2; ++m) {
      f32x4 sc0 = mfma16(kf0, qf[m], zero4);
      f32x4 sc1 = mfma16(kf1, qf[m], zero4);
      uint2 w0, w1;
      w0.x = cvtpk(__builtin_amdgcn_exp2f(sc0[0]), __builtin_amdgcn_exp2f(sc0[1]));
      w0.y = cvtpk(__builtin_amdgcn_exp2f(sc0[2]), __builtin_amdgcn_exp2f(sc0[3]));
      w1.x = cvtpk(__builtin_amdgcn_exp2f(sc1[0]), __builtin_amdgcn_exp2f(sc1[1]));
      w1.y = cvtpk(__builtin_amdgcn_exp2f(sc1[2]), __builtin_amdgcn_exp2f(sc1[3]));
      *reinterpret_cast<uint2*>(pb + (16 * m + lq) * 40 + g * 4)      = w0;
      *reinterpret_cast<uint2*>(pb + (16 * m + lq) * 40 + 16 + g * 4) = w1;
    }

    bf16x8 vf0 = *reinterpret_cast<const bf16x8*>(Vbh + (lq)      * SEQ + s0 + g * 8);
    bf16x8 vf1 = *reinterpret_cast<const bf16x8*>(Vbh + (16 + lq) * SEQ + s0 + g * 8);
    bf16x8 wf  = *reinterpret_cast<const bf16x8*>(wb + s0 + g * 8);

#pragma unroll
    for (int m = 0; m < 2; ++m) {
      bf16x8 pa = *reinterpret_cast<const bf16x8*>(pb + (16 * m + lq) * 40 + g * 8);
      o[m][0] = mfma16(pa, vf0, o[m][0]);
      o[m][1] = mfma16(pa, vf1, o[m][1]);
      den[m]  = mfma16(pa, wf,  den[m]);
    }
  }

  // stash partials into ol[wid]: [q32][d], denominator in col 32
#pragma unroll
  for (int m = 0; m < 2; ++m) {
#pragma unroll
    for (int r = 0; r < 4; ++r) {
      int q32 = 16 * m + 4 * g + r;
      ol[wid][q32][lq]      = o[m][0][r];
      ol[wid][q32][16 + lq] = o[m][1][r];
      if (lq == 0) ol[wid][q32][32] = den[m][r];
    }
  }
  __syncthreads();

  const int b = bh >> 3, h = bh & 7;
  for (int idx = tid; idx < 32 * 32; idx += 256) {
    int q = idx >> 5, d = idx & 31;
    float num = ol[0][q][d] + ol[1][q][d] + ol[2][q][d] + ol[3][q][d];
    float dd  = ol[0][q][32] + ol[1][q][32] + ol[2][q][32] + ol[3][q][32];
    AOb[(b * SEQ + q0 + q) * D_MODEL + h * DK + d] = f2bf(num / dd);
  }
}

// ---------------- output projection GEMM (128x64 tiles, full CU coverage) ----
__global__ __launch_bounds__(256) void out_gemm(
    const unsigned short* __restrict__ Ab, const float* __restrict__ Wo,
    const float* __restrict__ bo, float* __restrict__ out) {
  __shared__ __align__(16) unsigned short As[128 * 72];
  __shared__ __align__(16) unsigned short Bs[64 * 72];
  const int tid = threadIdx.x, lane = tid & 63, wid = tid >> 6;
  const int bm = blockIdx.x * 128;
  const int ncol = blockIdx.y * 64;
  const int waveM = wid * 32;

  f32x4 acc[2][4] = {};
  for (int kt = 0; kt < 4; ++kt) {
    __syncthreads();
#pragma unroll
    for (int p = 0; p < 4; ++p) {
      int c = p * 256 + tid;
      int r = c >> 3, kc = c & 7;
      uint4 va = *reinterpret_cast<const uint4*>(Ab + (size_t)(bm + r) * 256 + kt * 64 + kc * 8);
      *reinterpret_cast<uint4*>(&As[r * 72 + kc * 8]) = va;
    }
#pragma unroll
    for (int p = 0; p < 2; ++p) {
      int c = p * 256 + tid;
      int r = c >> 3, kc = c & 7;
      const float* wp_ = Wo + (size_t)(ncol + r) * 256 + kt * 64 + kc * 8;
      float4 g0 = *reinterpret_cast<const float4*>(wp_);
      float4 g1 = *reinterpret_cast<const float4*>(wp_ + 4);
      ushort4 b0, b1;
      b0.x = f2bf(g0.x); b0.y = f2bf(g0.y); b0.z = f2bf(g0.z); b0.w = f2bf(g0.w);
      b1.x = f2bf(g1.x); b1.y = f2bf(g1.y); b1.z = f2bf(g1.z); b1.w = f2bf(g1.w);
      *reinterpret_cast<ushort4*>(&Bs[r * 72 + kc * 8])     = b0;
      *reinterpret_cast<ushort4*>(&Bs[r * 72 + kc * 8 + 4]) = b1;
    }
    __syncthreads();
#pragma unroll
    for (int ks = 0; ks < 2; ++ks) {
      bf16x8 af[2], bf[4];
#pragma unroll
      for (int m = 0; m < 2; ++m)
        af[m] = *reinterpret_cast<const bf16x8*>(&As[(waveM + m * 16 + (lane & 15)) * 72 + ks * 32 + (lane >> 4) * 8]);
#pragma unroll
      for (int n = 0; n < 4; ++n)
        bf[n] = *reinterpret_cast<const bf16x8*>(&Bs[(n * 16 + (lane & 15)) * 72 + ks * 32 + (lane >> 4) * 8]);
#pragma unroll
      for (int m = 0; m < 2; ++m)
#pragma unroll
        for (int n = 0; n < 4; ++n) acc[m][n] = mfma16(af[m], bf[n], acc[m][n]);
    }
  }
#pragma unroll
  for (int m = 0; m < 2; ++m)
#pragma unroll
    for (int n = 0; n < 4; ++n) {
      int j = ncol + n * 16 + (lane & 15);
      float bias_v = bo[j];
#pragma unroll
      for (int r = 0; r < 4; ++r) {
        int i = bm + waveM + m * 16 + (lane >> 4) * 4 + r;
        out[(size_t)i * D_MODEL + j] = acc[m][n][r] + bias_v;
      }
    }
}

// ---------------- launcher ----------------
extern "C" void kernel_launch(void* const* d_in, const int* in_sizes, int n_in,
                              void* d_out, int out_size, void* d_ws, size_t ws_size,
                              hipStream_t stream) {
  const float* x  = (const float*)d_in[0];
  const float* cx = (const float*)d_in[1];
  const float* Wq = (const float*)d_in[2];
  const float* bq = (const float*)d_in[3];
  const float* Wk = (const float*)d_in[4];
  const float* bk = (const float*)d_in[5];
  const float* Wv = (const float*)d_in[6];
  const float* bv = (const float*)d_in[7];
  const float* Wo = (const float*)d_in[8];
  const float* bo = (const float*)d_in[9];
  float* out = (float*)d_out;
  char* ws = (char*)d_ws;

  unsigned short* Qb  = (unsigned short*)(ws + (size_t)4  * 1024 * 1024);
  unsigned short* Kb  = (unsigned short*)(ws + (size_t)8  * 1024 * 1024);
  unsigned short* Vt  = (unsigned short*)(ws + (size_t)12 * 1024 * 1024);
  unsigned short* AOb = (unsigned short*)(ws + (size_t)16 * 1024 * 1024);
  unsigned short* wb  = (unsigned short*)(ws + (size_t)21 * 1024 * 1024);

  qkv_gemm<<<dim3(64, 12), 256, 0, stream>>>(x, cx, Wq, Wk, Wv, bq, bk, bv, Qb, Kb, Vt, wb);
  attn_kernel<<<dim3(64, 32), 256, 0, stream>>>(Qb, Kb, Vt, wb, AOb);
  out_gemm<<<dim3(64, 4), 256, 0, stream>>>(AOb, Wo, bo, out);
}

// Round 18
// 81.696 us; speedup vs baseline: 1.0135x; 1.0135x over previous
//
#include <hip/hip_runtime.h>
#include <hip/hip_bf16.h>
#include <stdint.h>

#define D_MODEL 256
#define NHEAD   8
#define DK      32
#define BATCH   4
#define SEQ     2048
#define MROWS   (BATCH*SEQ)   // 8192

typedef float  f32x4  __attribute__((ext_vector_type(4)));
typedef __bf16 bf16x8 __attribute__((ext_vector_type(8)));

__device__ __forceinline__ unsigned short f2bf(float f) {
  unsigned int u = __float_as_uint(f);
  unsigned int r = (u + 0x7FFFu + ((u >> 16) & 1u)) >> 16;
  return (unsigned short)r;
}
__device__ __forceinline__ float bfbits2f(unsigned short b) {
  return __uint_as_float(((unsigned int)b) << 16);
}

__device__ __forceinline__ f32x4 mfma16(bf16x8 a, bf16x8 b, f32x4 c) {
  return __builtin_amdgcn_mfma_f32_16x16x32_bf16(a, b, c, 0, 0, 0);
}
__device__ __forceinline__ unsigned int cvtpk(float lo, float hi) {
  unsigned int r;
  asm("v_cvt_pk_bf16_f32 %0, %1, %2" : "=v"(r) : "v"(lo), "v"(hi));
  return r;
}

// scale folded into Wq/bq: (1/sqrt(32)) * log2(e)
#define QSCALE 0.2550599440097021f

// ---------------- fused QKV projection GEMM (128x64 tiles) -------------------
// y -> mat = y>>2 (0=Q,1=K,2=V), ncol=(y&3)*64. W casts fused into B staging;
// x cast fused into A staging. Q/K out: [bh][s][32]; V out: transposed +
// w-scaled: Vt[bh][d][s] = w_s*V[s][d]. y==0 blocks also materialize wb[].
__global__ __launch_bounds__(256) void qkv_gemm(
    const float* __restrict__ x, const float* __restrict__ cx,
    const float* __restrict__ Wq, const float* __restrict__ Wk,
    const float* __restrict__ Wv,
    const float* __restrict__ bq, const float* __restrict__ bk_, const float* __restrict__ bv,
    unsigned short* __restrict__ Qb, unsigned short* __restrict__ Kb,
    unsigned short* __restrict__ Vt, unsigned short* __restrict__ wb) {
  __shared__ __align__(16) unsigned short As[128 * 72];
  __shared__ __align__(16) unsigned short Bs[64 * 72];
  const int tid = threadIdx.x, lane = tid & 63, wid = tid >> 6;
  const int bm = blockIdx.x * 128;
  const int mat = blockIdx.y >> 2;
  const int ncol = (blockIdx.y & 3) * 64;
  const float* Wf = (mat == 0) ? Wq : ((mat == 1) ? Wk : Wv);
  const float* bias = (mat == 0) ? bq : ((mat == 1) ? bk_ : bv);
  const float bscale = (mat == 0) ? QSCALE : 1.0f;
  const int waveM = wid * 32;

  if (blockIdx.y == 0 && tid < 32) {
    int s = blockIdx.x * 32 + tid;
    wb[s] = (s == 0) ? (unsigned short)0 : f2bf(fabsf(cx[s] - cx[s - 1]));
  }

  f32x4 acc[2][4] = {};
  for (int kt = 0; kt < 4; ++kt) {
    __syncthreads();
#pragma unroll
    for (int p = 0; p < 4; ++p) {
      int c = p * 256 + tid;
      int r = c >> 3, kc = c & 7;
      const float* xp = x + (size_t)(bm + r) * 256 + kt * 64 + kc * 8;
      float4 f0 = *reinterpret_cast<const float4*>(xp);
      float4 f1 = *reinterpret_cast<const float4*>(xp + 4);
      ushort4 h0, h1;
      h0.x = f2bf(f0.x); h0.y = f2bf(f0.y); h0.z = f2bf(f0.z); h0.w = f2bf(f0.w);
      h1.x = f2bf(f1.x); h1.y = f2bf(f1.y); h1.z = f2bf(f1.z); h1.w = f2bf(f1.w);
      *reinterpret_cast<ushort4*>(&As[r * 72 + kc * 8])     = h0;
      *reinterpret_cast<ushort4*>(&As[r * 72 + kc * 8 + 4]) = h1;
    }
#pragma unroll
    for (int p = 0; p < 2; ++p) {
      int c = p * 256 + tid;
      int r = c >> 3, kc = c & 7;
      const float* wp_ = Wf + (size_t)(ncol + r) * 256 + kt * 64 + kc * 8;
      float4 g0 = *reinterpret_cast<const float4*>(wp_);
      float4 g1 = *reinterpret_cast<const float4*>(wp_ + 4);
      ushort4 b0, b1;
      b0.x = f2bf(g0.x * bscale); b0.y = f2bf(g0.y * bscale);
      b0.z = f2bf(g0.z * bscale); b0.w = f2bf(g0.w * bscale);
      b1.x = f2bf(g1.x * bscale); b1.y = f2bf(g1.y * bscale);
      b1.z = f2bf(g1.z * bscale); b1.w = f2bf(g1.w * bscale);
      *reinterpret_cast<ushort4*>(&Bs[r * 72 + kc * 8])     = b0;
      *reinterpret_cast<ushort4*>(&Bs[r * 72 + kc * 8 + 4]) = b1;
    }
    __syncthreads();
#pragma unroll
    for (int ks = 0; ks < 2; ++ks) {
      bf16x8 af[2], bf[4];
#pragma unroll
      for (int m = 0; m < 2; ++m)
        af[m] = *reinterpret_cast<const bf16x8*>(&As[(waveM + m * 16 + (lane & 15)) * 72 + ks * 32 + (lane >> 4) * 8]);
#pragma unroll
      for (int n = 0; n < 4; ++n)
        bf[n] = *reinterpret_cast<const bf16x8*>(&Bs[(n * 16 + (lane & 15)) * 72 + ks * 32 + (lane >> 4) * 8]);
#pragma unroll
      for (int m = 0; m < 2; ++m)
#pragma unroll
        for (int n = 0; n < 4; ++n) acc[m][n] = mfma16(af[m], bf[n], acc[m][n]);
    }
  }
#pragma unroll
  for (int m = 0; m < 2; ++m) {
    int i0 = bm + waveM + m * 16 + (lane >> 4) * 4;  // row of r=0 (mult of 4)
    int b = i0 >> 11, s = i0 & 2047;
    float wv4[4] = {0.f, 0.f, 0.f, 0.f};
    if (mat == 2) {
      float cm = (s > 0) ? cx[s - 1] : 0.0f;
      float c0 = cx[s], c1 = cx[s + 1], c2 = cx[s + 2], c3 = cx[s + 3];
      wv4[0] = (s > 0) ? bfbits2f(f2bf(fabsf(c0 - cm))) : 0.0f;
      wv4[1] = bfbits2f(f2bf(fabsf(c1 - c0)));
      wv4[2] = bfbits2f(f2bf(fabsf(c2 - c1)));
      wv4[3] = bfbits2f(f2bf(fabsf(c3 - c2)));
    }
#pragma unroll
    for (int n = 0; n < 4; ++n) {
      int j = ncol + n * 16 + (lane & 15);
      float bias_v = bias[j] * bscale;
      int h = j >> 5, d = j & 31;
      if (mat == 2) {
        ushort4 pk;
        pk.x = f2bf((acc[m][n][0] + bias_v) * wv4[0]);
        pk.y = f2bf((acc[m][n][1] + bias_v) * wv4[1]);
        pk.z = f2bf((acc[m][n][2] + bias_v) * wv4[2]);
        pk.w = f2bf((acc[m][n][3] + bias_v) * wv4[3]);
        *reinterpret_cast<ushort4*>(&Vt[((b * NHEAD + h) * DK + d) * SEQ + s]) = pk;
      } else {
        unsigned short* dst = (mat == 0) ? Qb : Kb;
#pragma unroll
        for (int r = 0; r < 4; ++r)
          dst[((b * NHEAD + h) * SEQ + s + r) * DK + d] = f2bf(acc[m][n][r] + bias_v);
      }
    }
  }
}

// ---------------- fused weighted attention (r8 body + XCD-affinity grid) -----
// Loop body VERBATIM round-8/14/17 (the only passing transport). ONE change:
// 1-D grid with the r12-PROVEN bijective XCD decode — all 64 q-tile blocks of
// each bh land on one XCD (4 bh/XCD, 1.5MB K/V < 4MB L2), so per-step loads
// are served from L2 (~200cy) instead of HBM (~900cy). Mechanism validated in
// r12 (FETCH 34.8->6.2MB); this isolates its timing effect from r12's
// confounded VALU-den regression.
__global__ __launch_bounds__(256, 4) void attn_kernel(
    const unsigned short* __restrict__ Qb, const unsigned short* __restrict__ Kb,
    const unsigned short* __restrict__ Vt, const unsigned short* __restrict__ wb,
    unsigned short* __restrict__ AOb) {
  __shared__ float ol[4][32][36];
  __shared__ __align__(16) unsigned short ps[4][2][32][40];
  const int tid = threadIdx.x, lane = tid & 63, wid = tid >> 6;
  const int g = lane >> 4, lq = lane & 15;

  // XCD-affinity decode: xcd = bid%8 serves bh in [4*xcd, 4*xcd+4)
  const int bid = blockIdx.x;
  const int xcd = bid & 7, slot = bid >> 3;        // 256 slots per XCD
  const int bh = xcd * 4 + (slot >> 6);
  const int q0 = (slot & 63) * 32;

  const unsigned short* Qbh = Qb + bh * SEQ * DK;
  const unsigned short* Kbh = Kb + bh * SEQ * DK;
  const unsigned short* Vbh = Vt + bh * DK * SEQ;

  bf16x8 qf[2];
  qf[0] = *reinterpret_cast<const bf16x8*>(Qbh + (q0 + lq) * DK + g * 8);
  qf[1] = *reinterpret_cast<const bf16x8*>(Qbh + (q0 + 16 + lq) * DK + g * 8);

  f32x4 o[2][2] = {};   // [q-tile m][d-tile n]
  f32x4 den[2] = {};
  const f32x4 zero4 = {0.f, 0.f, 0.f, 0.f};
  const int sbase = wid * (SEQ / 4);

#pragma unroll 2
  for (int st = 0; st < (SEQ / 4) / 32; ++st) {
    const int s0 = sbase + st * 32;
    bf16x8 kf0 = *reinterpret_cast<const bf16x8*>(Kbh + (s0 + lq) * DK + g * 8);
    bf16x8 kf1 = *reinterpret_cast<const bf16x8*>(Kbh + (s0 + 16 + lq) * DK + g * 8);

    unsigned short* pb = &ps[wid][st & 1][0][0];

#pragma unroll
    for (int m = 0; m < 2; ++m) {
      f32x4 sc0 = mfma16(kf0, qf[m], zero4);
      f32x4 sc1 = mfma16(kf1, qf[m], zero4);
      uint2 w0, w1;
      w0.x = cvtpk(__builtin_amdgcn_exp2f(sc0[0]), __builtin_amdgcn_exp2f(sc0[1]));
      w0.y = cvtpk(__builtin_amdgcn_exp2f(sc0[2]), __builtin_amdgcn_exp2f(sc0[3]));
      w1.x = cvtpk(__builtin_amdgcn_exp2f(sc1[0]), __builtin_amdgcn_exp2f(sc1[1]));
      w1.y = cvtpk(__builtin_amdgcn_exp2f(sc1[2]), __builtin_amdgcn_exp2f(sc1[3]));
      *reinterpret_cast<uint2*>(pb + (16 * m + lq) * 40 + g * 4)      = w0;
      *reinterpret_cast<uint2*>(pb + (16 * m + lq) * 40 + 16 + g * 4) = w1;
    }

    bf16x8 vf0 = *reinterpret_cast<const bf16x8*>(Vbh + (lq)      * SEQ + s0 + g * 8);
    bf16x8 vf1 = *reinterpret_cast<const bf16x8*>(Vbh + (16 + lq) * SEQ + s0 + g * 8);
    bf16x8 wf  = *reinterpret_cast<const bf16x8*>(wb + s0 + g * 8);

#pragma unroll
    for (int m = 0; m < 2; ++m) {
      bf16x8 pa = *reinterpret_cast<const bf16x8*>(pb + (16 * m + lq) * 40 + g * 8);
      o[m][0] = mfma16(pa, vf0, o[m][0]);
      o[m][1] = mfma16(pa, vf1, o[m][1]);
      den[m]  = mfma16(pa, wf,  den[m]);
    }
  }

  // stash partials into ol[wid]: [q32][d], denominator in col 32
#pragma unroll
  for (int m = 0; m < 2; ++m) {
#pragma unroll
    for (int r = 0; r < 4; ++r) {
      int q32 = 16 * m + 4 * g + r;
      ol[wid][q32][lq]      = o[m][0][r];
      ol[wid][q32][16 + lq] = o[m][1][r];
      if (lq == 0) ol[wid][q32][32] = den[m][r];
    }
  }
  __syncthreads();

  const int b = bh >> 3, h = bh & 7;
  for (int idx = tid; idx < 32 * 32; idx += 256) {
    int q = idx >> 5, d = idx & 31;
    float num = ol[0][q][d] + ol[1][q][d] + ol[2][q][d] + ol[3][q][d];
    float dd  = ol[0][q][32] + ol[1][q][32] + ol[2][q][32] + ol[3][q][32];
    AOb[(b * SEQ + q0 + q) * D_MODEL + h * DK + d] = f2bf(num / dd);
  }
}

// ---------------- output projection GEMM (128x64 tiles, full CU coverage) ----
__global__ __launch_bounds__(256) void out_gemm(
    const unsigned short* __restrict__ Ab, const float* __restrict__ Wo,
    const float* __restrict__ bo, float* __restrict__ out) {
  __shared__ __align__(16) unsigned short As[128 * 72];
  __shared__ __align__(16) unsigned short Bs[64 * 72];
  const int tid = threadIdx.x, lane = tid & 63, wid = tid >> 6;
  const int bm = blockIdx.x * 128;
  const int ncol = blockIdx.y * 64;
  const int waveM = wid * 32;

  f32x4 acc[2][4] = {};
  for (int kt = 0; kt < 4; ++kt) {
    __syncthreads();
#pragma unroll
    for (int p = 0; p < 4; ++p) {
      int c = p * 256 + tid;
      int r = c >> 3, kc = c & 7;
      uint4 va = *reinterpret_cast<const uint4*>(Ab + (size_t)(bm + r) * 256 + kt * 64 + kc * 8);
      *reinterpret_cast<uint4*>(&As[r * 72 + kc * 8]) = va;
    }
#pragma unroll
    for (int p = 0; p < 2; ++p) {
      int c = p * 256 + tid;
      int r = c >> 3, kc = c & 7;
      const float* wp_ = Wo + (size_t)(ncol + r) * 256 + kt * 64 + kc * 8;
      float4 g0 = *reinterpret_cast<const float4*>(wp_);
      float4 g1 = *reinterpret_cast<const float4*>(wp_ + 4);
      ushort4 b0, b1;
      b0.x = f2bf(g0.x); b0.y = f2bf(g0.y); b0.z = f2bf(g0.z); b0.w = f2bf(g0.w);
      b1.x = f2bf(g1.x); b1.y = f2bf(g1.y); b1.z = f2bf(g1.z); b1.w = f2bf(g1.w);
      *reinterpret_cast<ushort4*>(&Bs[r * 72 + kc * 8])     = b0;
      *reinterpret_cast<ushort4*>(&Bs[r * 72 + kc * 8 + 4]) = b1;
    }
    __syncthreads();
#pragma unroll
    for (int ks = 0; ks < 2; ++ks) {
      bf16x8 af[2], bf[4];
#pragma unroll
      for (int m = 0; m < 2; ++m)
        af[m] = *reinterpret_cast<const bf16x8*>(&As[(waveM + m * 16 + (lane & 15)) * 72 + ks * 32 + (lane >> 4) * 8]);
#pragma unroll
      for (int n = 0; n < 4; ++n)
        bf[n] = *reinterpret_cast<const bf16x8*>(&Bs[(n * 16 + (lane & 15)) * 72 + ks * 32 + (lane >> 4) * 8]);
#pragma unroll
      for (int m = 0; m < 2; ++m)
#pragma unroll
        for (int n = 0; n < 4; ++n) acc[m][n] = mfma16(af[m], bf[n], acc[m][n]);
    }
  }
#pragma unroll
  for (int m = 0; m < 2; ++m)
#pragma unroll
    for (int n = 0; n < 4; ++n) {
      int j = ncol + n * 16 + (lane & 15);
      float bias_v = bo[j];
#pragma unroll
      for (int r = 0; r < 4; ++r) {
        int i = bm + waveM + m * 16 + (lane >> 4) * 4 + r;
        out[(size_t)i * D_MODEL + j] = acc[m][n][r] + bias_v;
      }
    }
}

// ---------------- launcher ----------------
extern "C" void kernel_launch(void* const* d_in, const int* in_sizes, int n_in,
                              void* d_out, int out_size, void* d_ws, size_t ws_size,
                              hipStream_t stream) {
  const float* x  = (const float*)d_in[0];
  const float* cx = (const float*)d_in[1];
  const float* Wq = (const float*)d_in[2];
  const float* bq = (const float*)d_in[3];
  const float* Wk = (const float*)d_in[4];
  const float* bk = (const float*)d_in[5];
  const float* Wv = (const float*)d_in[6];
  const float* bv = (const float*)d_in[7];
  const float* Wo = (const float*)d_in[8];
  const float* bo = (const float*)d_in[9];
  float* out = (float*)d_out;
  char* ws = (char*)d_ws;

  unsigned short* Qb  = (unsigned short*)(ws + (size_t)4  * 1024 * 1024);
  unsigned short* Kb  = (unsigned short*)(ws + (size_t)8  * 1024 * 1024);
  unsigned short* Vt  = (unsigned short*)(ws + (size_t)12 * 1024 * 1024);
  unsigned short* AOb = (unsigned short*)(ws + (size_t)16 * 1024 * 1024);
  unsigned short* wb  = (unsigned short*)(ws + (size_t)21 * 1024 * 1024);

  qkv_gemm<<<dim3(64, 12), 256, 0, stream>>>(x, cx, Wq, Wk, Wv, bq, bk, bv, Qb, Kb, Vt, wb);
  attn_kernel<<<2048, 256, 0, stream>>>(Qb, Kb, Vt, wb, AOb);
  out_gemm<<<dim3(64, 4), 256, 0, stream>>>(AOb, Wo, bo, out);
}